// Round 3
// baseline (114.251 us; speedup 1.0000x reference)
//
#include <hip/hip_runtime.h>
#include <math.h>

#define N 4096
#define D 256
#define HALF 2048
#define MARGIN 0.3f

#define BM 64          // tile rows == cols
#define LDA 264        // padded LDS row length (bf16 elems): 528 B, 16B-aligned
#define NTB (HALF/BM)  // 32 tile-blocks per dimension

typedef __attribute__((ext_vector_type(8))) short bf16x8;  // 4 VGPRs
typedef __attribute__((ext_vector_type(4))) float f32x4;   // MFMA C/D

__device__ __forceinline__ unsigned short bf16_rne(float x) {
    unsigned int u = __float_as_uint(x);
    return (unsigned short)((u + 0x7fffu + ((u >> 16) & 1u)) >> 16);
}

// ---------------------------------------------------------------------------
// Fused: normalize 128 rows -> LDS bf16 (full K), MFMA cross-Gram, masked
// row/col max-min, write deterministic per-tile partials (no atomics, no init).
// Row stats -> first-half rows; col stats -> second-half rows (symmetry).
// ---------------------------------------------------------------------------
__global__ __launch_bounds__(256) void k_fused(const float* __restrict__ in,
                                               const int* __restrict__ tg,
                                               float* __restrict__ rowap,
                                               float* __restrict__ rowan,
                                               float* __restrict__ colap,
                                               float* __restrict__ colan) {
    __shared__ unsigned short As[BM * LDA];   // 33.8 KB
    __shared__ unsigned short Bs[BM * LDA];   // 33.8 KB
    __shared__ float sqv[128];                // sq for A rows [0:64) B rows [64:128)
    __shared__ int sra[BM], srn[BM], sca[BM], scn[BM];

    const int bi = blockIdx.y, bj = blockIdx.x;
    const int I0 = bi * BM;   // first-half rows
    const int J0 = bj * BM;   // second-half rows (= output cols)
    const int tid = threadIdx.x;
    const int wave = tid >> 6, lane = tid & 63;
    const int wm = wave >> 1, wn = wave & 1;       // 2x2 wave grid, 32x32 each
    const int lrow = lane & 15, lquad = lane >> 4;

    // ---- phase 1: normalize, convert, stage to LDS (one wave per row) ------
#pragma unroll 4
    for (int it = 0; it < 32; ++it) {
        int rr = wave * 32 + it;  // 0..127
        int g = (rr < 64) ? (I0 + rr) : (HALF + J0 + (rr - 64));
        float4 v = *(const float4*)&in[(size_t)g * D + lane * 4];
        float s = v.x * v.x + v.y * v.y + v.z * v.z + v.w * v.w;
#pragma unroll
        for (int o = 1; o < 64; o <<= 1) s += __shfl_xor(s, o, 64);
        float nrm = sqrtf(s);
        float inv = 1.0f / (nrm + 1e-6f);
        ushort4 h;
        h.x = bf16_rne(v.x * inv);
        h.y = bf16_rne(v.y * inv);
        h.z = bf16_rne(v.z * inv);
        h.w = bf16_rne(v.w * inv);
        unsigned short* dst = (rr < 64) ? &As[rr * LDA + lane * 4]
                                        : &Bs[(rr - 64) * LDA + lane * 4];
        *(ushort4*)dst = h;
        if (lane == 0) {
            float q = nrm * inv;
            sqv[rr] = q * q;
        }
    }
    __syncthreads();

    // ---- phase 2: MFMA over full K from LDS, no barriers -------------------
    f32x4 acc[2][2];
#pragma unroll
    for (int a = 0; a < 2; ++a)
#pragma unroll
        for (int b = 0; b < 2; ++b) acc[a][b] = (f32x4){0.f, 0.f, 0.f, 0.f};

#pragma unroll
    for (int k0 = 0; k0 < D; k0 += 32) {
        bf16x8 af[2], bfr[2];
#pragma unroll
        for (int mi = 0; mi < 2; ++mi)
            af[mi] = *(const bf16x8*)&As[(wm * 32 + mi * 16 + lrow) * LDA + k0 + lquad * 8];
#pragma unroll
        for (int nj = 0; nj < 2; ++nj)
            bfr[nj] = *(const bf16x8*)&Bs[(wn * 32 + nj * 16 + lrow) * LDA + k0 + lquad * 8];
#pragma unroll
        for (int mi = 0; mi < 2; ++mi)
#pragma unroll
            for (int nj = 0; nj < 2; ++nj)
                acc[mi][nj] = __builtin_amdgcn_mfma_f32_16x16x32_bf16(
                    af[mi], bfr[nj], acc[mi][nj], 0, 0, 0);
    }

    // ---- epilogue: distances + masked max/min ------------------------------
    // C/D layout per 16x16 tile: col = lane&15, row = lquad*4 + reg
    float sqi[2][4], sqj[2];
    int tgi[2][4], tgj[2];
#pragma unroll
    for (int mi = 0; mi < 2; ++mi)
#pragma unroll
        for (int r = 0; r < 4; ++r) {
            int lr = wm * 32 + mi * 16 + lquad * 4 + r;
            sqi[mi][r] = sqv[lr];
            tgi[mi][r] = tg[I0 + lr];
        }
#pragma unroll
    for (int nj = 0; nj < 2; ++nj) {
        int lc = wn * 32 + nj * 16 + lrow;
        sqj[nj] = sqv[64 + lc];
        tgj[nj] = tg[HALF + J0 + lc];
    }

    const float INF = __int_as_float(0x7f800000);
    float rap[2][4], ran[2][4], capv[2], canv[2];
#pragma unroll
    for (int mi = 0; mi < 2; ++mi)
#pragma unroll
        for (int r = 0; r < 4; ++r) { rap[mi][r] = 0.f; ran[mi][r] = INF; }
#pragma unroll
    for (int nj = 0; nj < 2; ++nj) { capv[nj] = 0.f; canv[nj] = INF; }

#pragma unroll
    for (int mi = 0; mi < 2; ++mi)
#pragma unroll
        for (int nj = 0; nj < 2; ++nj)
#pragma unroll
            for (int r = 0; r < 4; ++r) {
                float d2 = sqi[mi][r] + sqj[nj] - 2.0f * acc[mi][nj][r];
                float d = sqrtf(fmaxf(d2, 1e-6f));
                if (tgi[mi][r] == tgj[nj]) {
                    rap[mi][r] = fmaxf(rap[mi][r], d);
                    capv[nj] = fmaxf(capv[nj], d);
                } else {
                    ran[mi][r] = fminf(ran[mi][r], d);
                    canv[nj] = fminf(canv[nj], d);
                }
            }

    // shuffle pre-reduce: rows across 16 col-lanes; cols across 4 quads
#pragma unroll
    for (int mi = 0; mi < 2; ++mi)
#pragma unroll
        for (int r = 0; r < 4; ++r)
#pragma unroll
            for (int o = 1; o < 16; o <<= 1) {
                rap[mi][r] = fmaxf(rap[mi][r], __shfl_xor(rap[mi][r], o, 64));
                ran[mi][r] = fminf(ran[mi][r], __shfl_xor(ran[mi][r], o, 64));
            }
#pragma unroll
    for (int nj = 0; nj < 2; ++nj)
#pragma unroll
        for (int o = 16; o < 64; o <<= 1) {
            capv[nj] = fmaxf(capv[nj], __shfl_xor(capv[nj], o, 64));
            canv[nj] = fminf(canv[nj], __shfl_xor(canv[nj], o, 64));
        }

    if (tid < BM) { sra[tid] = 0; srn[tid] = 0x7f800000;
                    sca[tid] = 0; scn[tid] = 0x7f800000; }
    __syncthreads();
    if (lrow == 0) {  // one lane per (quad,mi,r) row; 2-way contention (wn)
#pragma unroll
        for (int mi = 0; mi < 2; ++mi)
#pragma unroll
            for (int r = 0; r < 4; ++r) {
                int lr = wm * 32 + mi * 16 + lquad * 4 + r;
                atomicMax(&sra[lr], __float_as_int(rap[mi][r]));
                atomicMin(&srn[lr], __float_as_int(ran[mi][r]));
            }
    }
    if (lquad == 0) {  // one lane per col; 2-way contention (wm)
#pragma unroll
        for (int nj = 0; nj < 2; ++nj) {
            int lc = wn * 32 + nj * 16 + lrow;
            atomicMax(&sca[lc], __float_as_int(capv[nj]));
            atomicMin(&scn[lc], __float_as_int(canv[nj]));
        }
    }
    __syncthreads();
    // deterministic partial writes: each slot written by exactly one block
    if (tid < BM) {
        rowap[bj * HALF + I0 + tid] = __int_as_float(sra[tid]);
        rowan[bj * HALF + I0 + tid] = __int_as_float(srn[tid]);
        colap[bi * HALF + J0 + tid] = __int_as_float(sca[tid]);
        colan[bi * HALF + J0 + tid] = __int_as_float(scn[tid]);
    }
}

// ---------------------------------------------------------------------------
// Reduce partials per row -> relu term -> per-block sum. 16 blocks x 256.
// ---------------------------------------------------------------------------
__global__ __launch_bounds__(256) void k_reduce(const float* __restrict__ rowap,
                                                const float* __restrict__ rowan,
                                                const float* __restrict__ colap,
                                                const float* __restrict__ colan,
                                                float* __restrict__ bsum) {
    const int t = threadIdx.x;
    const int gid = blockIdx.x * 256 + t;  // one row per thread, 0..4095
    const float INF = __int_as_float(0x7f800000);
    float ap = 0.f, an = INF;
    if (gid < HALF) {
#pragma unroll
        for (int b = 0; b < NTB; ++b) {
            ap = fmaxf(ap, rowap[b * HALF + gid]);
            an = fminf(an, rowan[b * HALF + gid]);
        }
    } else {
        int j = gid - HALF;
#pragma unroll
        for (int b = 0; b < NTB; ++b) {
            ap = fmaxf(ap, colap[b * HALF + j]);
            an = fminf(an, colan[b * HALF + j]);
        }
    }
    if (an == INF) an = 1.0f;  // neg_any == false fallback
    float v = ap - an + MARGIN;
    float s = (v > 0.f) ? v : 0.f;
#pragma unroll
    for (int o = 32; o > 0; o >>= 1) s += __shfl_down(s, o, 64);
    __shared__ float wsum[4];
    if ((t & 63) == 0) wsum[t >> 6] = s;
    __syncthreads();
    if (t == 0) bsum[blockIdx.x] = wsum[0] + wsum[1] + wsum[2] + wsum[3];
}

// ---------------------------------------------------------------------------
// Final: sum 16 partials -> mean.
// ---------------------------------------------------------------------------
__global__ void k_final(const float* __restrict__ bsum, float* __restrict__ out) {
    if (threadIdx.x == 0) {
        float tot = 0.f;
#pragma unroll
        for (int b = 0; b < 16; ++b) tot += bsum[b];
        out[0] = tot / (float)N;
    }
}

extern "C" void kernel_launch(void* const* d_in, const int* in_sizes, int n_in,
                              void* d_out, int out_size, void* d_ws, size_t ws_size,
                              hipStream_t stream) {
    const float* in = (const float*)d_in[0];
    const int* tg = (const int*)d_in[1];
    float* out = (float*)d_out;

    float* rowap = (float*)d_ws;             // [NTB][HALF]
    float* rowan = rowap + NTB * HALF;
    float* colap = rowan + NTB * HALF;
    float* colan = colap + NTB * HALF;
    float* bsum  = colan + NTB * HALF;       // [16]

    k_fused<<<dim3(NTB, NTB), 256, 0, stream>>>(in, tg, rowap, rowan, colap, colan);
    k_reduce<<<16, 256, 0, stream>>>(rowap, rowan, colap, colan, bsum);
    k_final<<<1, 64, 0, stream>>>(bsum, out);
}

// Round 4
// 83.387 us; speedup vs baseline: 1.3701x; 1.3701x over previous
//
#include <hip/hip_runtime.h>
#include <math.h>

#define N 4096
#define D 256
#define HALF 2048
#define MARGIN 0.3f

#define BM 64          // tile rows == cols
#define NTB (HALF/BM)  // 32 tile-blocks per dimension

typedef __attribute__((ext_vector_type(8))) short bf16x8;  // 4 VGPRs
typedef __attribute__((ext_vector_type(4))) float f32x4;   // MFMA C/D

__device__ __forceinline__ unsigned short bf16_rne(float x) {
    unsigned int u = __float_as_uint(x);
    return (unsigned short)((u + 0x7fffu + ((u >> 16) & 1u)) >> 16);
}

// async global->LDS, 16B per lane; LDS dest = uniform base + lane*16
__device__ __forceinline__ void load_lds16(const unsigned short* g,
                                           unsigned short* l) {
    __builtin_amdgcn_global_load_lds(
        (const __attribute__((address_space(1))) void*)g,
        (__attribute__((address_space(3))) void*)l, 16, 0, 0);
}

// ---------------------------------------------------------------------------
// Kernel 1: row L2-normalize -> bf16 (natural layout) + sq. Wave per row.
// ---------------------------------------------------------------------------
__global__ __launch_bounds__(256) void k_norm(const float* __restrict__ in,
                                              unsigned short* __restrict__ xnb,
                                              float* __restrict__ sq) {
    const int wave = threadIdx.x >> 6, lane = threadIdx.x & 63;
    const int row = blockIdx.x * 4 + wave;
    float4 v = *(const float4*)&in[(size_t)row * D + lane * 4];
    float s = v.x * v.x + v.y * v.y + v.z * v.z + v.w * v.w;
#pragma unroll
    for (int o = 1; o < 64; o <<= 1) s += __shfl_xor(s, o, 64);
    float nrm = sqrtf(s);
    float inv = 1.0f / (nrm + 1e-6f);
    ushort4 h;
    h.x = bf16_rne(v.x * inv);
    h.y = bf16_rne(v.y * inv);
    h.z = bf16_rne(v.z * inv);
    h.w = bf16_rne(v.w * inv);
    *(ushort4*)&xnb[(size_t)row * D + lane * 4] = h;
    if (lane == 0) {
        float q = nrm * inv;
        sq[row] = q * q;  // (||v||/(||v||+eps))^2
    }
}

// ---------------------------------------------------------------------------
// Kernel 2: full-K one-shot LDS staging (global_load_lds, XOR chunk swizzle),
// 32 MFMAs, fused distance + masked row/col max-min, deterministic partials.
// Row stats -> first-half rows; col stats -> second-half rows (symmetry).
// ---------------------------------------------------------------------------
__global__ __launch_bounds__(256) void k_tile(const unsigned short* __restrict__ xnb,
                                              const float* __restrict__ sq,
                                              const int* __restrict__ tg,
                                              float* __restrict__ rowap,
                                              float* __restrict__ rowan,
                                              float* __restrict__ colap,
                                              float* __restrict__ colan) {
    __shared__ unsigned short As[BM * D];   // 32 KB, row-major, chunk-swizzled
    __shared__ unsigned short Bs[BM * D];   // 32 KB
    __shared__ int sra[BM], srn[BM], sca[BM], scn[BM];

    const int bi = blockIdx.y, bj = blockIdx.x;
    const int I0 = bi * BM;   // first-half rows
    const int J0 = bj * BM;   // second-half rows (= output cols)
    const int tid = threadIdx.x;
    const int wave = tid >> 6, lane = tid & 63;
    const int wm = wave >> 1, wn = wave & 1;       // 2x2 wave grid, 32x32 each
    const int lrow = lane & 15, lquad = lane >> 4;

    // ---- staging: each wave loads 2 A-rows + 2 B-rows per iteration --------
    // LDS slot (lane&31) of row gets global chunk ((lane&31) ^ (row&7)):
    // stored_slot = chunk ^ (row&7)  => 8 consecutive rows cover all 32 banks.
    {
        const int slot = lane & 31;
        const int rsub = lane >> 5;              // 0..1 within the row pair
        const int swz = (wave * 2 + rsub) & 7;   // == row_local & 7 (i*8 drops)
        const int goff = ((slot ^ swz) << 3);    // chunk*8 bf16 elems
#pragma unroll
        for (int i = 0; i < 8; ++i) {
            int r0 = i * 8 + wave * 2;           // local row pair base
            int rl = r0 + rsub;
            load_lds16(&xnb[(size_t)(I0 + rl) * D + goff], &As[r0 * D]);
            load_lds16(&xnb[(size_t)(HALF + J0 + rl) * D + goff], &Bs[r0 * D]);
        }
    }
    __syncthreads();

    // ---- MFMA over full K from LDS, no barriers ----------------------------
    f32x4 acc[2][2];
#pragma unroll
    for (int a = 0; a < 2; ++a)
#pragma unroll
        for (int b = 0; b < 2; ++b) acc[a][b] = (f32x4){0.f, 0.f, 0.f, 0.f};

    const int rsw = lrow & 7;  // row&7 for fragment rows (wm*32+mi*16 == 0 mod 8)
#pragma unroll
    for (int k0 = 0; k0 < D; k0 += 32) {
        const int c0 = (k0 >> 3) + lquad;        // natural chunk index
        const int co = ((c0 ^ rsw) << 3);        // swizzled elem offset in row
        bf16x8 af[2], bfr[2];
#pragma unroll
        for (int mi = 0; mi < 2; ++mi)
            af[mi] = *(const bf16x8*)&As[(wm * 32 + mi * 16 + lrow) * D + co];
#pragma unroll
        for (int nj = 0; nj < 2; ++nj)
            bfr[nj] = *(const bf16x8*)&Bs[(wn * 32 + nj * 16 + lrow) * D + co];
#pragma unroll
        for (int mi = 0; mi < 2; ++mi)
#pragma unroll
            for (int nj = 0; nj < 2; ++nj)
                acc[mi][nj] = __builtin_amdgcn_mfma_f32_16x16x32_bf16(
                    af[mi], bfr[nj], acc[mi][nj], 0, 0, 0);
    }

    // ---- epilogue: distances + masked max/min ------------------------------
    // C/D layout per 16x16 tile: col = lane&15, row = lquad*4 + reg
    float sqi[2][4], sqj[2];
    int tgi[2][4], tgj[2];
#pragma unroll
    for (int mi = 0; mi < 2; ++mi)
#pragma unroll
        for (int r = 0; r < 4; ++r) {
            int lr = wm * 32 + mi * 16 + lquad * 4 + r;
            sqi[mi][r] = sq[I0 + lr];
            tgi[mi][r] = tg[I0 + lr];
        }
#pragma unroll
    for (int nj = 0; nj < 2; ++nj) {
        int lc = wn * 32 + nj * 16 + lrow;
        sqj[nj] = sq[HALF + J0 + lc];
        tgj[nj] = tg[HALF + J0 + lc];
    }

    const float INF = __int_as_float(0x7f800000);
    float rap[2][4], ran[2][4], capv[2], canv[2];
#pragma unroll
    for (int mi = 0; mi < 2; ++mi)
#pragma unroll
        for (int r = 0; r < 4; ++r) { rap[mi][r] = 0.f; ran[mi][r] = INF; }
#pragma unroll
    for (int nj = 0; nj < 2; ++nj) { capv[nj] = 0.f; canv[nj] = INF; }

#pragma unroll
    for (int mi = 0; mi < 2; ++mi)
#pragma unroll
        for (int nj = 0; nj < 2; ++nj)
#pragma unroll
            for (int r = 0; r < 4; ++r) {
                float d2 = sqi[mi][r] + sqj[nj] - 2.0f * acc[mi][nj][r];
                float d = sqrtf(fmaxf(d2, 1e-6f));
                if (tgi[mi][r] == tgj[nj]) {
                    rap[mi][r] = fmaxf(rap[mi][r], d);
                    capv[nj] = fmaxf(capv[nj], d);
                } else {
                    ran[mi][r] = fminf(ran[mi][r], d);
                    canv[nj] = fminf(canv[nj], d);
                }
            }

    // shuffle pre-reduce: rows across 16 col-lanes; cols across 4 quads
#pragma unroll
    for (int mi = 0; mi < 2; ++mi)
#pragma unroll
        for (int r = 0; r < 4; ++r)
#pragma unroll
            for (int o = 1; o < 16; o <<= 1) {
                rap[mi][r] = fmaxf(rap[mi][r], __shfl_xor(rap[mi][r], o, 64));
                ran[mi][r] = fminf(ran[mi][r], __shfl_xor(ran[mi][r], o, 64));
            }
#pragma unroll
    for (int nj = 0; nj < 2; ++nj)
#pragma unroll
        for (int o = 16; o < 64; o <<= 1) {
            capv[nj] = fmaxf(capv[nj], __shfl_xor(capv[nj], o, 64));
            canv[nj] = fminf(canv[nj], __shfl_xor(canv[nj], o, 64));
        }

    if (tid < BM) { sra[tid] = 0; srn[tid] = 0x7f800000;
                    sca[tid] = 0; scn[tid] = 0x7f800000; }
    __syncthreads();
    if (lrow == 0) {  // one lane per (quad,mi,r) row; 2-way contention (wn)
#pragma unroll
        for (int mi = 0; mi < 2; ++mi)
#pragma unroll
            for (int r = 0; r < 4; ++r) {
                int lr = wm * 32 + mi * 16 + lquad * 4 + r;
                atomicMax(&sra[lr], __float_as_int(rap[mi][r]));
                atomicMin(&srn[lr], __float_as_int(ran[mi][r]));
            }
    }
    if (lquad == 0) {  // one lane per col; 2-way contention (wm)
#pragma unroll
        for (int nj = 0; nj < 2; ++nj) {
            int lc = wn * 32 + nj * 16 + lrow;
            atomicMax(&sca[lc], __float_as_int(capv[nj]));
            atomicMin(&scn[lc], __float_as_int(canv[nj]));
        }
    }
    __syncthreads();
    // deterministic partial writes: each slot written by exactly one block
    if (tid < BM) {
        rowap[bj * HALF + I0 + tid] = __int_as_float(sra[tid]);
        rowan[bj * HALF + I0 + tid] = __int_as_float(srn[tid]);
        colap[bi * HALF + J0 + tid] = __int_as_float(sca[tid]);
        colan[bi * HALF + J0 + tid] = __int_as_float(scn[tid]);
    }
}

// ---------------------------------------------------------------------------
// Reduce partials per row -> relu term -> per-block sum. 16 blocks x 256.
// ---------------------------------------------------------------------------
__global__ __launch_bounds__(256) void k_reduce(const float* __restrict__ rowap,
                                                const float* __restrict__ rowan,
                                                const float* __restrict__ colap,
                                                const float* __restrict__ colan,
                                                float* __restrict__ bsum) {
    const int t = threadIdx.x;
    const int gid = blockIdx.x * 256 + t;  // one row per thread, 0..4095
    const float INF = __int_as_float(0x7f800000);
    float ap = 0.f, an = INF;
    if (gid < HALF) {
#pragma unroll
        for (int b = 0; b < NTB; ++b) {
            ap = fmaxf(ap, rowap[b * HALF + gid]);
            an = fminf(an, rowan[b * HALF + gid]);
        }
    } else {
        int j = gid - HALF;
#pragma unroll
        for (int b = 0; b < NTB; ++b) {
            ap = fmaxf(ap, colap[b * HALF + j]);
            an = fminf(an, colan[b * HALF + j]);
        }
    }
    if (an == INF) an = 1.0f;  // neg_any == false fallback
    float v = ap - an + MARGIN;
    float s = (v > 0.f) ? v : 0.f;
#pragma unroll
    for (int o = 32; o > 0; o >>= 1) s += __shfl_down(s, o, 64);
    __shared__ float wsum[4];
    if ((t & 63) == 0) wsum[t >> 6] = s;
    __syncthreads();
    if (t == 0) bsum[blockIdx.x] = wsum[0] + wsum[1] + wsum[2] + wsum[3];
}

// ---------------------------------------------------------------------------
// Final: sum 16 partials -> mean.
// ---------------------------------------------------------------------------
__global__ void k_final(const float* __restrict__ bsum, float* __restrict__ out) {
    if (threadIdx.x == 0) {
        float tot = 0.f;
#pragma unroll
        for (int b = 0; b < 16; ++b) tot += bsum[b];
        out[0] = tot / (float)N;
    }
}

extern "C" void kernel_launch(void* const* d_in, const int* in_sizes, int n_in,
                              void* d_out, int out_size, void* d_ws, size_t ws_size,
                              hipStream_t stream) {
    const float* in = (const float*)d_in[0];
    const int* tg = (const int*)d_in[1];
    float* out = (float*)d_out;

    unsigned short* xnb = (unsigned short*)d_ws;     // N*D bf16 (2 MB)
    float* sq = (float*)(xnb + (size_t)N * D);       // N floats
    float* rowap = sq + N;                           // [NTB][HALF] each
    float* rowan = rowap + NTB * HALF;
    float* colap = rowan + NTB * HALF;
    float* colan = colap + NTB * HALF;
    float* bsum  = colan + NTB * HALF;               // [16]

    k_norm<<<N / 4, 256, 0, stream>>>(in, xnb, sq);
    k_tile<<<dim3(NTB, NTB), 256, 0, stream>>>(xnb, sq, tg,
                                               rowap, rowan, colap, colan);
    k_reduce<<<16, 256, 0, stream>>>(rowap, rowan, colap, colan, bsum);
    k_final<<<1, 64, 0, stream>>>(bsum, out);
}

// Round 5
// 82.442 us; speedup vs baseline: 1.3858x; 1.0115x over previous
//
#include <hip/hip_runtime.h>
#include <math.h>

#define N 4096
#define D 256
#define HALF 2048
#define MARGIN 0.3f

#define BM 64          // tile rows == cols
#define NTB (HALF/BM)  // 32 tile-blocks per dimension
#define LDA 264        // padded LDS row (bf16 elems): 528 B, 16B-aligned

typedef __attribute__((ext_vector_type(8))) short bf16x8;  // 4 VGPRs
typedef __attribute__((ext_vector_type(4))) float f32x4;   // MFMA C/D

__device__ __forceinline__ unsigned short bf16_rne(float x) {
    unsigned int u = __float_as_uint(x);
    return (unsigned short)((u + 0x7fffu + ((u >> 16) & 1u)) >> 16);
}

// ---------------------------------------------------------------------------
// Kernel 1: row L2-normalize -> bf16 + sq. Wave per row. Also zero-inits the
// final-reduction accumulator/counter (stream order covers k_reduce).
// ---------------------------------------------------------------------------
__global__ __launch_bounds__(256) void k_norm(const float* __restrict__ in,
                                              unsigned short* __restrict__ xnb,
                                              float* __restrict__ sq,
                                              float* __restrict__ acc_sum,
                                              int* __restrict__ acc_cnt) {
    const int wave = threadIdx.x >> 6, lane = threadIdx.x & 63;
    const int row = blockIdx.x * 4 + wave;
    float4 v = *(const float4*)&in[(size_t)row * D + lane * 4];
    float s = v.x * v.x + v.y * v.y + v.z * v.z + v.w * v.w;
#pragma unroll
    for (int o = 1; o < 64; o <<= 1) s += __shfl_xor(s, o, 64);
    float nrm = sqrtf(s);
    float inv = 1.0f / (nrm + 1e-6f);
    ushort4 h;
    h.x = bf16_rne(v.x * inv);
    h.y = bf16_rne(v.y * inv);
    h.z = bf16_rne(v.z * inv);
    h.w = bf16_rne(v.w * inv);
    *(ushort4*)&xnb[(size_t)row * D + lane * 4] = h;
    if (lane == 0) {
        float q = nrm * inv;
        sq[row] = q * q;  // (||v||/(||v||+eps))^2
    }
    if (blockIdx.x == 0 && threadIdx.x == 0) {
        *acc_sum = 0.f;
        *acc_cnt = 0;
    }
}

// ---------------------------------------------------------------------------
// Kernel 2: one-shot full-K staging (coalesced uint4 -> VGPR -> padded LDS),
// 32 back-to-back MFMAs, fused distance + masked row/col max-min,
// deterministic per-tile partials (no global atomics, no init needed).
// Row stats -> first-half rows; col stats -> second-half rows (symmetry).
// ---------------------------------------------------------------------------
__global__ __launch_bounds__(256) void k_tile(const unsigned short* __restrict__ xnb,
                                              const float* __restrict__ sq,
                                              const int* __restrict__ tg,
                                              float* __restrict__ rowap,
                                              float* __restrict__ rowan,
                                              float* __restrict__ colap,
                                              float* __restrict__ colan) {
    __shared__ unsigned short As[BM * LDA];   // 33.8 KB
    __shared__ unsigned short Bs[BM * LDA];   // 33.8 KB
    __shared__ int sra[BM], srn[BM], sca[BM], scn[BM];

    const int bi = blockIdx.y, bj = blockIdx.x;
    const int I0 = bi * BM;   // first-half rows
    const int J0 = bj * BM;   // second-half rows (= output cols)
    const int tid = threadIdx.x;
    const int wave = tid >> 6, lane = tid & 63;
    const int wm = wave >> 1, wn = wave & 1;       // 2x2 wave grid, 32x32 each
    const int lrow = lane & 15, lquad = lane >> 4;

    // ---- staging: lane-ordered coalesced loads, VGPR round-trip ------------
    {
        const int chunk = tid & 31;   // 16B chunk within a 512B row
        const int rp = tid >> 5;      // 0..7
        const unsigned short* Agp = xnb + (size_t)I0 * D;
        const unsigned short* Bgp = xnb + (size_t)(HALF + J0) * D;
        uint4 av[8], bv[8];
#pragma unroll
        for (int i = 0; i < 8; ++i) {
            int r = i * 8 + rp;
            av[i] = *(const uint4*)&Agp[(size_t)r * D + chunk * 8];
            bv[i] = *(const uint4*)&Bgp[(size_t)r * D + chunk * 8];
        }
#pragma unroll
        for (int i = 0; i < 8; ++i) {
            int r = i * 8 + rp;
            *(uint4*)&As[r * LDA + chunk * 8] = av[i];
            *(uint4*)&Bs[r * LDA + chunk * 8] = bv[i];
        }
    }
    __syncthreads();

    // ---- MFMA over full K from LDS, no barriers ----------------------------
    f32x4 acc[2][2];
#pragma unroll
    for (int a = 0; a < 2; ++a)
#pragma unroll
        for (int b = 0; b < 2; ++b) acc[a][b] = (f32x4){0.f, 0.f, 0.f, 0.f};

#pragma unroll
    for (int k0 = 0; k0 < D; k0 += 32) {
        bf16x8 af[2], bfr[2];
#pragma unroll
        for (int mi = 0; mi < 2; ++mi)
            af[mi] = *(const bf16x8*)&As[(wm * 32 + mi * 16 + lrow) * LDA + k0 + lquad * 8];
#pragma unroll
        for (int nj = 0; nj < 2; ++nj)
            bfr[nj] = *(const bf16x8*)&Bs[(wn * 32 + nj * 16 + lrow) * LDA + k0 + lquad * 8];
#pragma unroll
        for (int mi = 0; mi < 2; ++mi)
#pragma unroll
            for (int nj = 0; nj < 2; ++nj)
                acc[mi][nj] = __builtin_amdgcn_mfma_f32_16x16x32_bf16(
                    af[mi], bfr[nj], acc[mi][nj], 0, 0, 0);
    }

    // ---- epilogue: distances + masked max/min ------------------------------
    // C/D layout per 16x16 tile: col = lane&15 (n), row = lquad*4 + reg (m)
    float sqi[2][4], sqj[2];
    int tgi[2][4], tgj[2];
#pragma unroll
    for (int mi = 0; mi < 2; ++mi)
#pragma unroll
        for (int r = 0; r < 4; ++r) {
            int lr = wm * 32 + mi * 16 + lquad * 4 + r;
            sqi[mi][r] = sq[I0 + lr];
            tgi[mi][r] = tg[I0 + lr];
        }
#pragma unroll
    for (int nj = 0; nj < 2; ++nj) {
        int lc = wn * 32 + nj * 16 + lrow;
        sqj[nj] = sq[HALF + J0 + lc];
        tgj[nj] = tg[HALF + J0 + lc];
    }

    const float INF = __int_as_float(0x7f800000);
    float rap[2][4], ran[2][4], capv[2], canv[2];
#pragma unroll
    for (int mi = 0; mi < 2; ++mi)
#pragma unroll
        for (int r = 0; r < 4; ++r) { rap[mi][r] = 0.f; ran[mi][r] = INF; }
#pragma unroll
    for (int nj = 0; nj < 2; ++nj) { capv[nj] = 0.f; canv[nj] = INF; }

#pragma unroll
    for (int mi = 0; mi < 2; ++mi)
#pragma unroll
        for (int nj = 0; nj < 2; ++nj)
#pragma unroll
            for (int r = 0; r < 4; ++r) {
                float d2 = sqi[mi][r] + sqj[nj] - 2.0f * acc[mi][nj][r];
                float d = sqrtf(fmaxf(d2, 1e-6f));
                if (tgi[mi][r] == tgj[nj]) {
                    rap[mi][r] = fmaxf(rap[mi][r], d);
                    capv[nj] = fmaxf(capv[nj], d);
                } else {
                    ran[mi][r] = fminf(ran[mi][r], d);
                    canv[nj] = fminf(canv[nj], d);
                }
            }

    // shuffle pre-reduce: rows across 16 col-lanes; cols across 4 quads
#pragma unroll
    for (int mi = 0; mi < 2; ++mi)
#pragma unroll
        for (int r = 0; r < 4; ++r)
#pragma unroll
            for (int o = 1; o < 16; o <<= 1) {
                rap[mi][r] = fmaxf(rap[mi][r], __shfl_xor(rap[mi][r], o, 64));
                ran[mi][r] = fminf(ran[mi][r], __shfl_xor(ran[mi][r], o, 64));
            }
#pragma unroll
    for (int nj = 0; nj < 2; ++nj)
#pragma unroll
        for (int o = 16; o < 64; o <<= 1) {
            capv[nj] = fmaxf(capv[nj], __shfl_xor(capv[nj], o, 64));
            canv[nj] = fminf(canv[nj], __shfl_xor(canv[nj], o, 64));
        }

    if (tid < BM) { sra[tid] = 0; srn[tid] = 0x7f800000;
                    sca[tid] = 0; scn[tid] = 0x7f800000; }
    __syncthreads();
    if (lrow == 0) {  // one lane per (quad,mi,r) row; 2-way contention (wn)
#pragma unroll
        for (int mi = 0; mi < 2; ++mi)
#pragma unroll
            for (int r = 0; r < 4; ++r) {
                int lr = wm * 32 + mi * 16 + lquad * 4 + r;
                atomicMax(&sra[lr], __float_as_int(rap[mi][r]));
                atomicMin(&srn[lr], __float_as_int(ran[mi][r]));
            }
    }
    if (lquad == 0) {  // one lane per col; 2-way contention (wm)
#pragma unroll
        for (int nj = 0; nj < 2; ++nj) {
            int lc = wn * 32 + nj * 16 + lrow;
            atomicMax(&sca[lc], __float_as_int(capv[nj]));
            atomicMin(&scn[lc], __float_as_int(canv[nj]));
        }
    }
    __syncthreads();
    // deterministic partial writes: each slot written by exactly one block
    if (tid < BM) {
        rowap[bj * HALF + I0 + tid] = __int_as_float(sra[tid]);
        rowan[bj * HALF + I0 + tid] = __int_as_float(srn[tid]);
        colap[bi * HALF + J0 + tid] = __int_as_float(sca[tid]);
        colan[bi * HALF + J0 + tid] = __int_as_float(scn[tid]);
    }
}

// ---------------------------------------------------------------------------
// Kernel 3: fold partials per row -> relu term -> wave sum -> device atomic;
// last block writes the mean. 64 blocks x 64 threads (1 wave each).
// ---------------------------------------------------------------------------
__global__ __launch_bounds__(64) void k_reduce(const float* __restrict__ rowap,
                                               const float* __restrict__ rowan,
                                               const float* __restrict__ colap,
                                               const float* __restrict__ colan,
                                               float* __restrict__ acc_sum,
                                               int* __restrict__ acc_cnt,
                                               float* __restrict__ out) {
    const int lane = threadIdx.x;
    const int gid = blockIdx.x * 64 + lane;  // one row per thread, 0..4095
    const float INF = __int_as_float(0x7f800000);
    float ap = 0.f, an = INF;
    if (gid < HALF) {
#pragma unroll
        for (int b = 0; b < NTB; ++b) {
            ap = fmaxf(ap, rowap[b * HALF + gid]);
            an = fminf(an, rowan[b * HALF + gid]);
        }
    } else {
        int j = gid - HALF;
#pragma unroll
        for (int b = 0; b < NTB; ++b) {
            ap = fmaxf(ap, colap[b * HALF + j]);
            an = fminf(an, colan[b * HALF + j]);
        }
    }
    if (an == INF) an = 1.0f;  // neg_any == false fallback
    float v = ap - an + MARGIN;
    float s = (v > 0.f) ? v : 0.f;
#pragma unroll
    for (int o = 1; o < 64; o <<= 1) s += __shfl_xor(s, o, 64);
    if (lane == 0) {
        atomicAdd(acc_sum, s);           // device-scope by default
        __threadfence();
        int old = atomicAdd(acc_cnt, 1);
        if (old == 63) {                 // last block: all 64 sums are in
            float tot = atomicAdd(acc_sum, 0.0f);
            out[0] = tot / (float)N;
        }
    }
}

extern "C" void kernel_launch(void* const* d_in, const int* in_sizes, int n_in,
                              void* d_out, int out_size, void* d_ws, size_t ws_size,
                              hipStream_t stream) {
    const float* in = (const float*)d_in[0];
    const int* tg = (const int*)d_in[1];
    float* out = (float*)d_out;

    unsigned short* xnb = (unsigned short*)d_ws;     // N*D bf16 (2 MB)
    float* sq = (float*)(xnb + (size_t)N * D);       // N floats
    float* rowap = sq + N;                           // [NTB][HALF] each
    float* rowan = rowap + NTB * HALF;
    float* colap = rowan + NTB * HALF;
    float* colan = colap + NTB * HALF;
    float* acc_sum = colan + NTB * HALF;
    int* acc_cnt = (int*)(acc_sum + 1);

    k_norm<<<N / 4, 256, 0, stream>>>(in, xnb, sq, acc_sum, acc_cnt);
    k_tile<<<dim3(NTB, NTB), 256, 0, stream>>>(xnb, sq, tg,
                                               rowap, rowan, colap, colan);
    k_reduce<<<64, 64, 0, stream>>>(rowap, rowan, colap, colan,
                                    acc_sum, acc_cnt, out);
}

// Round 6
// 80.244 us; speedup vs baseline: 1.4238x; 1.0274x over previous
//
#include <hip/hip_runtime.h>
#include <math.h>

#define N 4096
#define D 256
#define HALF 2048
#define MARGIN 0.3f

#define BM 64          // tile rows == cols
#define NTB (HALF/BM)  // 32 tile-blocks per dimension

typedef __attribute__((ext_vector_type(8))) short bf16x8;  // 4 VGPRs
typedef __attribute__((ext_vector_type(4))) float f32x4;   // MFMA C/D

__device__ __forceinline__ unsigned short bf16_rne(float x) {
    unsigned int u = __float_as_uint(x);
    return (unsigned short)((u + 0x7fffu + ((u >> 16) & 1u)) >> 16);
}

// ---------------------------------------------------------------------------
// Kernel 1: row L2-normalize -> bf16 + sq; init ap/an and the final-reduce
// accumulator (stream order makes these visible to k_tile / k_reduce).
// ---------------------------------------------------------------------------
__global__ __launch_bounds__(256) void k_norm(const float* __restrict__ in,
                                              unsigned short* __restrict__ xnb,
                                              float* __restrict__ sq,
                                              int* __restrict__ ap,
                                              int* __restrict__ an,
                                              float* __restrict__ acc_sum,
                                              int* __restrict__ acc_cnt) {
    const int wave = threadIdx.x >> 6, lane = threadIdx.x & 63;
    const int row = blockIdx.x * 4 + wave;
    float4 v = *(const float4*)&in[(size_t)row * D + lane * 4];
    float s = v.x * v.x + v.y * v.y + v.z * v.z + v.w * v.w;
#pragma unroll
    for (int o = 1; o < 64; o <<= 1) s += __shfl_xor(s, o, 64);
    float nrm = sqrtf(s);
    float inv = 1.0f / (nrm + 1e-6f);
    ushort4 h;
    h.x = bf16_rne(v.x * inv);
    h.y = bf16_rne(v.y * inv);
    h.z = bf16_rne(v.z * inv);
    h.w = bf16_rne(v.w * inv);
    *(ushort4*)&xnb[(size_t)row * D + lane * 4] = h;
    if (lane == 0) {
        float q = nrm * inv;
        sq[row] = q * q;            // (||v||/(||v||+eps))^2
        ap[row] = 0;                // bits(0.0f) == pos_any-false fallback
        an[row] = 0x7f800000;       // +inf sentinel for neg_any-false
    }
    if (blockIdx.x == 0 && threadIdx.x == 0) {
        *acc_sum = 0.f;
        *acc_cnt = 0;
    }
}

// ---------------------------------------------------------------------------
// Kernel 2: barrier-free MFMA cross-Gram. A/B fragments loaded DIRECTLY from
// global (L2-resident, 16B/lane in exact MFMA layout) — no LDS tiles, no
// staging, no K-loop barriers. Fused distance + masked row/col max-min,
// shuffle pre-reduce, LDS combine, global atomics.
// Row stats -> first-half rows; col stats -> second-half rows (symmetry).
// ---------------------------------------------------------------------------
__global__ __launch_bounds__(256) void k_tile(const unsigned short* __restrict__ xnb,
                                              const float* __restrict__ sq,
                                              const int* __restrict__ tg,
                                              int* __restrict__ ap,
                                              int* __restrict__ an) {
    __shared__ int sra[BM], srn[BM], sca[BM], scn[BM];

    const int bi = blockIdx.y, bj = blockIdx.x;
    const int I0 = bi * BM;   // first-half rows
    const int J0 = bj * BM;   // second-half rows (= output cols)
    const int tid = threadIdx.x;
    const int wave = tid >> 6, lane = tid & 63;
    const int wm = wave >> 1, wn = wave & 1;       // 2x2 wave grid, 32x32 each
    const int lrow = lane & 15, lquad = lane >> 4;

    // fragment row pointers: lane reads 16B at (row, k0 + lquad*8)
    const unsigned short* A0 = xnb + (size_t)(I0 + wm * 32 + lrow) * D + lquad * 8;
    const unsigned short* A1 = A0 + (size_t)16 * D;
    const unsigned short* B0 = xnb + (size_t)(HALF + J0 + wn * 32 + lrow) * D + lquad * 8;
    const unsigned short* B1 = B0 + (size_t)16 * D;

    f32x4 acc[2][2];
#pragma unroll
    for (int a = 0; a < 2; ++a)
#pragma unroll
        for (int b = 0; b < 2; ++b) acc[a][b] = (f32x4){0.f, 0.f, 0.f, 0.f};

#pragma unroll
    for (int k0 = 0; k0 < D; k0 += 32) {
        bf16x8 a0 = *(const bf16x8*)(A0 + k0);
        bf16x8 a1 = *(const bf16x8*)(A1 + k0);
        bf16x8 b0 = *(const bf16x8*)(B0 + k0);
        bf16x8 b1 = *(const bf16x8*)(B1 + k0);
        acc[0][0] = __builtin_amdgcn_mfma_f32_16x16x32_bf16(a0, b0, acc[0][0], 0, 0, 0);
        acc[0][1] = __builtin_amdgcn_mfma_f32_16x16x32_bf16(a0, b1, acc[0][1], 0, 0, 0);
        acc[1][0] = __builtin_amdgcn_mfma_f32_16x16x32_bf16(a1, b0, acc[1][0], 0, 0, 0);
        acc[1][1] = __builtin_amdgcn_mfma_f32_16x16x32_bf16(a1, b1, acc[1][1], 0, 0, 0);
    }

    // ---- epilogue: distances + masked max/min ------------------------------
    // C/D layout per 16x16 tile: col = lane&15 (n), row = lquad*4 + reg (m)
    float sqi[2][4], sqj[2];
    int tgi[2][4], tgj[2];
#pragma unroll
    for (int mi = 0; mi < 2; ++mi)
#pragma unroll
        for (int r = 0; r < 4; ++r) {
            int lr = wm * 32 + mi * 16 + lquad * 4 + r;
            sqi[mi][r] = sq[I0 + lr];
            tgi[mi][r] = tg[I0 + lr];
        }
#pragma unroll
    for (int nj = 0; nj < 2; ++nj) {
        int lc = wn * 32 + nj * 16 + lrow;
        sqj[nj] = sq[HALF + J0 + lc];
        tgj[nj] = tg[HALF + J0 + lc];
    }

    const float INF = __int_as_float(0x7f800000);
    float rap[2][4], ran[2][4], capv[2], canv[2];
#pragma unroll
    for (int mi = 0; mi < 2; ++mi)
#pragma unroll
        for (int r = 0; r < 4; ++r) { rap[mi][r] = 0.f; ran[mi][r] = INF; }
#pragma unroll
    for (int nj = 0; nj < 2; ++nj) { capv[nj] = 0.f; canv[nj] = INF; }

#pragma unroll
    for (int mi = 0; mi < 2; ++mi)
#pragma unroll
        for (int nj = 0; nj < 2; ++nj)
#pragma unroll
            for (int r = 0; r < 4; ++r) {
                float d2 = sqi[mi][r] + sqj[nj] - 2.0f * acc[mi][nj][r];
                float d = sqrtf(fmaxf(d2, 1e-6f));
                if (tgi[mi][r] == tgj[nj]) {
                    rap[mi][r] = fmaxf(rap[mi][r], d);
                    capv[nj] = fmaxf(capv[nj], d);
                } else {
                    ran[mi][r] = fminf(ran[mi][r], d);
                    canv[nj] = fminf(canv[nj], d);
                }
            }

    // shuffle pre-reduce: rows across 16 col-lanes; cols across 4 quads
#pragma unroll
    for (int mi = 0; mi < 2; ++mi)
#pragma unroll
        for (int r = 0; r < 4; ++r)
#pragma unroll
            for (int o = 1; o < 16; o <<= 1) {
                rap[mi][r] = fmaxf(rap[mi][r], __shfl_xor(rap[mi][r], o, 64));
                ran[mi][r] = fminf(ran[mi][r], __shfl_xor(ran[mi][r], o, 64));
            }
#pragma unroll
    for (int nj = 0; nj < 2; ++nj)
#pragma unroll
        for (int o = 16; o < 64; o <<= 1) {
            capv[nj] = fmaxf(capv[nj], __shfl_xor(capv[nj], o, 64));
            canv[nj] = fminf(canv[nj], __shfl_xor(canv[nj], o, 64));
        }

    if (tid < BM) { sra[tid] = 0; srn[tid] = 0x7f800000;
                    sca[tid] = 0; scn[tid] = 0x7f800000; }
    __syncthreads();
    if (lrow == 0) {  // one lane per (quad,mi,r) row; 2-way contention (wn)
#pragma unroll
        for (int mi = 0; mi < 2; ++mi)
#pragma unroll
            for (int r = 0; r < 4; ++r) {
                int lr = wm * 32 + mi * 16 + lquad * 4 + r;
                atomicMax(&sra[lr], __float_as_int(rap[mi][r]));
                atomicMin(&srn[lr], __float_as_int(ran[mi][r]));
            }
    }
    if (lquad == 0) {  // one lane per col; 2-way contention (wm)
#pragma unroll
        for (int nj = 0; nj < 2; ++nj) {
            int lc = wn * 32 + nj * 16 + lrow;
            atomicMax(&sca[lc], __float_as_int(capv[nj]));
            atomicMin(&scn[lc], __float_as_int(canv[nj]));
        }
    }
    __syncthreads();
    if (tid < BM) {
        atomicMax(&ap[I0 + tid], sra[tid]);
        atomicMin(&an[I0 + tid], srn[tid]);
        atomicMax(&ap[HALF + J0 + tid], sca[tid]);
        atomicMin(&an[HALF + J0 + tid], scn[tid]);
    }
}

// ---------------------------------------------------------------------------
// Kernel 3: relu term per row -> wave sum -> device atomic; last block of 64
// writes the mean. 64 blocks x 64 threads.
// ---------------------------------------------------------------------------
__global__ __launch_bounds__(64) void k_reduce(const int* __restrict__ ap,
                                               const int* __restrict__ an,
                                               float* __restrict__ acc_sum,
                                               int* __restrict__ acc_cnt,
                                               float* __restrict__ out) {
    const int lane = threadIdx.x;
    const int gid = blockIdx.x * 64 + lane;  // one row per thread
    float dap = __int_as_float(ap[gid]);
    int anb = an[gid];
    float dan = (anb == 0x7f800000) ? 1.0f : __int_as_float(anb);
    float v = dap - dan + MARGIN;
    float s = (v > 0.f) ? v : 0.f;
#pragma unroll
    for (int o = 1; o < 64; o <<= 1) s += __shfl_xor(s, o, 64);
    if (lane == 0) {
        atomicAdd(acc_sum, s);           // device-scope by default
        __threadfence();
        int old = atomicAdd(acc_cnt, 1);
        if (old == 63) {                 // last block: all 64 sums are in
            float tot = atomicAdd(acc_sum, 0.0f);
            out[0] = tot / (float)N;
        }
    }
}

extern "C" void kernel_launch(void* const* d_in, const int* in_sizes, int n_in,
                              void* d_out, int out_size, void* d_ws, size_t ws_size,
                              hipStream_t stream) {
    const float* in = (const float*)d_in[0];
    const int* tg = (const int*)d_in[1];
    float* out = (float*)d_out;

    unsigned short* xnb = (unsigned short*)d_ws;     // N*D bf16 (2 MB)
    float* sq = (float*)(xnb + (size_t)N * D);       // N floats
    int* ap = (int*)(sq + N);                        // N ints
    int* an = ap + N;                                // N ints
    float* acc_sum = (float*)(an + N);
    int* acc_cnt = (int*)(acc_sum + 1);

    k_norm<<<N / 4, 256, 0, stream>>>(in, xnb, sq, ap, an, acc_sum, acc_cnt);
    k_tile<<<dim3(NTB, NTB), 256, 0, stream>>>(xnb, sq, tg, ap, an);
    k_reduce<<<64, 64, 0, stream>>>(ap, an, acc_sum, acc_cnt, out);
}

// Round 7
// 72.932 us; speedup vs baseline: 1.5665x; 1.1003x over previous
//
#include <hip/hip_runtime.h>
#include <math.h>

#define N 4096
#define D 256
#define HALF 2048
#define MARGIN 0.3f

#define BM 64          // tile rows == cols
#define BK 32          // k-step == MFMA K
#define NTB (HALF/BM)  // 32 tile-blocks per dimension
#define LDB 40         // padded LDS row (bf16 elems): 80 B stride

typedef __attribute__((ext_vector_type(8))) short bf16x8;  // 4 VGPRs
typedef __attribute__((ext_vector_type(4))) float f32x4;   // MFMA C/D

__device__ __forceinline__ unsigned short bf16_rne(float x) {
    unsigned int u = __float_as_uint(x);
    return (unsigned short)((u + 0x7fffu + ((u >> 16) & 1u)) >> 16);
}

// ---------------------------------------------------------------------------
// Kernel 1: row L2-normalize -> bf16 + sq; init ap/an and final-reduce state.
// ---------------------------------------------------------------------------
__global__ __launch_bounds__(256) void k_norm(const float* __restrict__ in,
                                              unsigned short* __restrict__ xnb,
                                              float* __restrict__ sq,
                                              int* __restrict__ ap,
                                              int* __restrict__ an,
                                              float* __restrict__ acc_sum,
                                              int* __restrict__ acc_cnt) {
    const int wave = threadIdx.x >> 6, lane = threadIdx.x & 63;
    const int row = blockIdx.x * 4 + wave;
    float4 v = *(const float4*)&in[(size_t)row * D + lane * 4];
    float s = v.x * v.x + v.y * v.y + v.z * v.z + v.w * v.w;
#pragma unroll
    for (int o = 1; o < 64; o <<= 1) s += __shfl_xor(s, o, 64);
    float nrm = sqrtf(s);
    float inv = 1.0f / (nrm + 1e-6f);
    ushort4 h;
    h.x = bf16_rne(v.x * inv);
    h.y = bf16_rne(v.y * inv);
    h.z = bf16_rne(v.z * inv);
    h.w = bf16_rne(v.w * inv);
    *(ushort4*)&xnb[(size_t)row * D + lane * 4] = h;
    if (lane == 0) {
        float q = nrm * inv;
        sq[row] = q * q;            // (||v||/(||v||+eps))^2
        ap[row] = 0;                // bits(0.0f) == pos_any-false fallback
        an[row] = 0x7f800000;       // +inf sentinel for neg_any-false
    }
    if (blockIdx.x == 0 && threadIdx.x == 0) {
        *acc_sum = 0.f;
        *acc_cnt = 0;
    }
}

// ---------------------------------------------------------------------------
// Kernel 2: R2-structure barrier K-loop, upgraded to double-buffered LDS with
// register prefetch (1 barrier/step). LDS-fed MFMAs; 4 blocks/CU residency
// overlaps one block's staging with another's compute.
// Row stats -> first-half rows; col stats -> second-half rows (symmetry).
// ---------------------------------------------------------------------------
__global__ __launch_bounds__(256, 4) void k_tile(const unsigned short* __restrict__ xnb,
                                                 const float* __restrict__ sq,
                                                 const int* __restrict__ tg,
                                                 int* __restrict__ ap,
                                                 int* __restrict__ an) {
    __shared__ unsigned short As[2][BM * LDB];   // 5 KB each
    __shared__ unsigned short Bs[2][BM * LDB];
    __shared__ int sra[BM], srn[BM], sca[BM], scn[BM];

    const int bi = blockIdx.y, bj = blockIdx.x;
    const int I0 = bi * BM;   // first-half rows
    const int J0 = bj * BM;   // second-half rows (= output cols)
    const int tid = threadIdx.x;
    const int wave = tid >> 6, lane = tid & 63;
    const int wm = wave >> 1, wn = wave & 1;       // 2x2 wave grid, 32x32 each
    const int lrow = lane & 15, lquad = lane >> 4;

    // staging coords: thread -> (row 0..63, 16B chunk 0..3) of the k-slab
    const int srow = tid >> 2, schunk = (tid & 3) * 8;
    const unsigned short* Agp = xnb + (size_t)(I0 + srow) * D + schunk;
    const unsigned short* Bgp = xnb + (size_t)(HALF + J0 + srow) * D + schunk;
    unsigned short* Asp0 = &As[0][srow * LDB + schunk];
    unsigned short* Bsp0 = &Bs[0][srow * LDB + schunk];
    unsigned short* Asp1 = &As[1][srow * LDB + schunk];
    unsigned short* Bsp1 = &Bs[1][srow * LDB + schunk];

    f32x4 acc[2][2];
#pragma unroll
    for (int a = 0; a < 2; ++a)
#pragma unroll
        for (int b = 0; b < 2; ++b) acc[a][b] = (f32x4){0.f, 0.f, 0.f, 0.f};

    // prologue: stage k-slab 0
    {
        uint4 a0 = *(const uint4*)Agp;
        uint4 b0 = *(const uint4*)Bgp;
        *(uint4*)Asp0 = a0;
        *(uint4*)Bsp0 = b0;
    }
    __syncthreads();

#pragma unroll
    for (int s = 0; s < D / BK; ++s) {
        const int p = s & 1;
        uint4 an_, bn_;
        if (s < D / BK - 1) {  // prefetch next slab while computing this one
            an_ = *(const uint4*)(Agp + (s + 1) * BK);
            bn_ = *(const uint4*)(Bgp + (s + 1) * BK);
        }
        bf16x8 af[2], bfr[2];
#pragma unroll
        for (int mi = 0; mi < 2; ++mi)
            af[mi] = *(const bf16x8*)&As[p][(wm * 32 + mi * 16 + lrow) * LDB + lquad * 8];
#pragma unroll
        for (int nj = 0; nj < 2; ++nj)
            bfr[nj] = *(const bf16x8*)&Bs[p][(wn * 32 + nj * 16 + lrow) * LDB + lquad * 8];
#pragma unroll
        for (int mi = 0; mi < 2; ++mi)
#pragma unroll
            for (int nj = 0; nj < 2; ++nj)
                acc[mi][nj] = __builtin_amdgcn_mfma_f32_16x16x32_bf16(
                    af[mi], bfr[nj], acc[mi][nj], 0, 0, 0);
        if (s < D / BK - 1) {
            if (p) { *(uint4*)Asp0 = an_; *(uint4*)Bsp0 = bn_; }
            else   { *(uint4*)Asp1 = an_; *(uint4*)Bsp1 = bn_; }
            __syncthreads();
        }
    }

    // ---- epilogue: distances + masked max/min ------------------------------
    // C/D layout per 16x16 tile: col = lane&15 (n), row = lquad*4 + reg (m)
    float sqi[2][4], sqj[2];
    int tgi[2][4], tgj[2];
#pragma unroll
    for (int mi = 0; mi < 2; ++mi)
#pragma unroll
        for (int r = 0; r < 4; ++r) {
            int lr = wm * 32 + mi * 16 + lquad * 4 + r;
            sqi[mi][r] = sq[I0 + lr];
            tgi[mi][r] = tg[I0 + lr];
        }
#pragma unroll
    for (int nj = 0; nj < 2; ++nj) {
        int lc = wn * 32 + nj * 16 + lrow;
        sqj[nj] = sq[HALF + J0 + lc];
        tgj[nj] = tg[HALF + J0 + lc];
    }

    const float INF = __int_as_float(0x7f800000);
    float rap[2][4], ran[2][4], capv[2], canv[2];
#pragma unroll
    for (int mi = 0; mi < 2; ++mi)
#pragma unroll
        for (int r = 0; r < 4; ++r) { rap[mi][r] = 0.f; ran[mi][r] = INF; }
#pragma unroll
    for (int nj = 0; nj < 2; ++nj) { capv[nj] = 0.f; canv[nj] = INF; }

#pragma unroll
    for (int mi = 0; mi < 2; ++mi)
#pragma unroll
        for (int nj = 0; nj < 2; ++nj)
#pragma unroll
            for (int r = 0; r < 4; ++r) {
                float d2 = sqi[mi][r] + sqj[nj] - 2.0f * acc[mi][nj][r];
                float d = sqrtf(fmaxf(d2, 1e-6f));
                if (tgi[mi][r] == tgj[nj]) {
                    rap[mi][r] = fmaxf(rap[mi][r], d);
                    capv[nj] = fmaxf(capv[nj], d);
                } else {
                    ran[mi][r] = fminf(ran[mi][r], d);
                    canv[nj] = fminf(canv[nj], d);
                }
            }

    // shuffle pre-reduce: rows across 16 col-lanes; cols across 4 quads
#pragma unroll
    for (int mi = 0; mi < 2; ++mi)
#pragma unroll
        for (int r = 0; r < 4; ++r)
#pragma unroll
            for (int o = 1; o < 16; o <<= 1) {
                rap[mi][r] = fmaxf(rap[mi][r], __shfl_xor(rap[mi][r], o, 64));
                ran[mi][r] = fminf(ran[mi][r], __shfl_xor(ran[mi][r], o, 64));
            }
#pragma unroll
    for (int nj = 0; nj < 2; ++nj)
#pragma unroll
        for (int o = 16; o < 64; o <<= 1) {
            capv[nj] = fmaxf(capv[nj], __shfl_xor(capv[nj], o, 64));
            canv[nj] = fminf(canv[nj], __shfl_xor(canv[nj], o, 64));
        }

    if (tid < BM) { sra[tid] = 0; srn[tid] = 0x7f800000;
                    sca[tid] = 0; scn[tid] = 0x7f800000; }
    __syncthreads();
    if (lrow == 0) {  // one lane per (quad,mi,r) row; 2-way contention (wn)
#pragma unroll
        for (int mi = 0; mi < 2; ++mi)
#pragma unroll
            for (int r = 0; r < 4; ++r) {
                int lr = wm * 32 + mi * 16 + lquad * 4 + r;
                atomicMax(&sra[lr], __float_as_int(rap[mi][r]));
                atomicMin(&srn[lr], __float_as_int(ran[mi][r]));
            }
    }
    if (lquad == 0) {  // one lane per col; 2-way contention (wm)
#pragma unroll
        for (int nj = 0; nj < 2; ++nj) {
            int lc = wn * 32 + nj * 16 + lrow;
            atomicMax(&sca[lc], __float_as_int(capv[nj]));
            atomicMin(&scn[lc], __float_as_int(canv[nj]));
        }
    }
    __syncthreads();
    if (tid < BM) {
        atomicMax(&ap[I0 + tid], sra[tid]);
        atomicMin(&an[I0 + tid], srn[tid]);
        atomicMax(&ap[HALF + J0 + tid], sca[tid]);
        atomicMin(&an[HALF + J0 + tid], scn[tid]);
    }
}

// ---------------------------------------------------------------------------
// Kernel 3: relu term per row -> wave sum -> device atomic; last block of 64
// writes the mean. 64 blocks x 64 threads.
// ---------------------------------------------------------------------------
__global__ __launch_bounds__(64) void k_reduce(const int* __restrict__ ap,
                                               const int* __restrict__ an,
                                               float* __restrict__ acc_sum,
                                               int* __restrict__ acc_cnt,
                                               float* __restrict__ out) {
    const int lane = threadIdx.x;
    const int gid = blockIdx.x * 64 + lane;  // one row per thread
    float dap = __int_as_float(ap[gid]);
    int anb = an[gid];
    float dan = (anb == 0x7f800000) ? 1.0f : __int_as_float(anb);
    float v = dap - dan + MARGIN;
    float s = (v > 0.f) ? v : 0.f;
#pragma unroll
    for (int o = 1; o < 64; o <<= 1) s += __shfl_xor(s, o, 64);
    if (lane == 0) {
        atomicAdd(acc_sum, s);           // device-scope by default
        __threadfence();
        int old = atomicAdd(acc_cnt, 1);
        if (old == 63) {                 // last block: all 64 sums are in
            float tot = atomicAdd(acc_sum, 0.0f);
            out[0] = tot / (float)N;
        }
    }
}

extern "C" void kernel_launch(void* const* d_in, const int* in_sizes, int n_in,
                              void* d_out, int out_size, void* d_ws, size_t ws_size,
                              hipStream_t stream) {
    const float* in = (const float*)d_in[0];
    const int* tg = (const int*)d_in[1];
    float* out = (float*)d_out;

    unsigned short* xnb = (unsigned short*)d_ws;     // N*D bf16 (2 MB)
    float* sq = (float*)(xnb + (size_t)N * D);       // N floats
    int* ap = (int*)(sq + N);                        // N ints
    int* an = ap + N;                                // N ints
    float* acc_sum = (float*)(an + N);
    int* acc_cnt = (int*)(acc_sum + 1);

    k_norm<<<N / 4, 256, 0, stream>>>(in, xnb, sq, ap, an, acc_sum, acc_cnt);
    k_tile<<<dim3(NTB, NTB), 256, 0, stream>>>(xnb, sq, tg, ap, an);
    k_reduce<<<64, 64, 0, stream>>>(ap, an, acc_sum, acc_cnt, out);
}